// Round 2
// baseline (108864.905 us; speedup 1.0000x reference)
//
#include <hip/hip_runtime.h>

typedef unsigned int  uint32;
typedef unsigned short bf16u;

__device__ __forceinline__ float fast_tanh(float x) {
    x = fminf(9.f, fmaxf(-9.f, x));
    float e = __expf(2.f * x);
    return (e - 1.f) / (e + 1.f);
}
__device__ __forceinline__ float sigmoidf(float x) {
    return 1.f / (1.f + __expf(-x));
}
__device__ __forceinline__ bf16u f2bf(float f) {
    uint32 u = __float_as_uint(f);
    u += 0x7fffu + ((u >> 16) & 1u);
    return (bf16u)(u >> 16);
}
__device__ __forceinline__ float bf2f(bf16u u) {
    return __uint_as_float(((uint32)u) << 16);
}
__device__ __forceinline__ uint32 pack2bf(float lo, float hi) {
    return (uint32)f2bf(lo) | ((uint32)f2bf(hi) << 16);
}
__device__ __forceinline__ float bflo(uint32 p) { return __uint_as_float(p << 16); }
__device__ __forceinline__ float bfhi(uint32 p) { return __uint_as_float(p & 0xffff0000u); }

// ---------------------------------------------------------------------------
// Embedding + context projection -> inp [rt=t*32+b][256] bf16 (emb || ctx)
// ---------------------------------------------------------------------------
__global__ void __launch_bounds__(128) embed_ctx_kernel(
    const int* __restrict__ x, const float* __restrict__ ctx,
    const float* __restrict__ emb, const float* __restrict__ ctxW,
    const float* __restrict__ ctxb, bf16u* __restrict__ inp)
{
    const int r0 = blockIdx.x * 16;       // 16 consecutive rt rows (same t)
    const int tid = threadIdx.x;          // 0..127 = output channel
    __shared__ float cs[16][301];
    __shared__ int xs[16];
    for (int i = tid; i < 16 * 300; i += 128) {
        int row = i / 300, k = i - row * 300;
        int rt = r0 + row, b = rt & 31, t = rt >> 5;
        cs[row][k] = ctx[((size_t)b * 1024 + t) * 300 + k];
    }
    if (tid < 16) {
        int rt = r0 + tid;
        xs[tid] = x[(rt & 31) * 1024 + (rt >> 5)];
    }
    __syncthreads();
    float acc[16];
    #pragma unroll
    for (int row = 0; row < 16; ++row) acc[row] = 0.f;
    for (int k = 0; k < 300; ++k) {
        float w = ctxW[tid * 300 + k];
        #pragma unroll
        for (int row = 0; row < 16; ++row) acc[row] = fmaf(w, cs[row][k], acc[row]);
    }
    float bb = ctxb[tid];
    for (int row = 0; row < 16; ++row) {
        size_t base = (size_t)(r0 + row) * 256;
        inp[base + tid]       = f2bf(emb[xs[row] * 128 + tid]);
        inp[base + 128 + tid] = f2bf(acc[row] + bb);
    }
}

// ---------------------------------------------------------------------------
// GEMM: C[M,N] = A[M,K](bf16) @ W[N,K]^T(f32) (+bias1+bias2)
// A split at K0 between A0/A1. mode: 0=f32 out, 1=bf16 out, 2=bf16+tanh,
// 3=f32 out with row permutation rt=(t*32+b) -> (b*1024+t) (logits).
// BM=BN=64, BK=16, 256 threads, 4x4 microtile.
// ---------------------------------------------------------------------------
__global__ void __launch_bounds__(256) gemm_kernel(
    const bf16u* __restrict__ A0, const bf16u* __restrict__ A1, int K0,
    const float* __restrict__ W, const float* __restrict__ bias1,
    const float* __restrict__ bias2, void* __restrict__ Cout,
    int M, int N, int K, int mode)
{
    __shared__ float As[16][68];
    __shared__ float Ws[16][68];
    const int tid = threadIdx.x;
    const int bn = blockIdx.x * 64, bm = blockIdx.y * 64;
    const int tx = tid & 15, ty = tid >> 4;
    const int loadRow = tid >> 2, loadK4 = (tid & 3) * 4;
    float acc[4][4] = {};
    for (int k0 = 0; k0 < K; k0 += 16) {
        const bf16u* Ab; int kb, lda;
        if (k0 < K0) { Ab = A0; kb = k0; lda = K0; }
        else         { Ab = A1; kb = k0 - K0; lda = K - K0; }
        ushort4 av = *(const ushort4*)(Ab + (size_t)(bm + loadRow) * lda + kb + loadK4);
        float4 wv = make_float4(0.f, 0.f, 0.f, 0.f);
        int wrow = bn + loadRow;
        if (wrow < N) wv = *(const float4*)(W + (size_t)wrow * K + k0 + loadK4);
        __syncthreads();
        As[loadK4 + 0][loadRow] = bf2f(av.x);
        As[loadK4 + 1][loadRow] = bf2f(av.y);
        As[loadK4 + 2][loadRow] = bf2f(av.z);
        As[loadK4 + 3][loadRow] = bf2f(av.w);
        Ws[loadK4 + 0][loadRow] = wv.x;
        Ws[loadK4 + 1][loadRow] = wv.y;
        Ws[loadK4 + 2][loadRow] = wv.z;
        Ws[loadK4 + 3][loadRow] = wv.w;
        __syncthreads();
        #pragma unroll
        for (int kk = 0; kk < 16; ++kk) {
            float4 a = *(const float4*)&As[kk][ty * 4];
            float4 w = *(const float4*)&Ws[kk][tx * 4];
            acc[0][0] = fmaf(a.x, w.x, acc[0][0]);
            acc[0][1] = fmaf(a.x, w.y, acc[0][1]);
            acc[0][2] = fmaf(a.x, w.z, acc[0][2]);
            acc[0][3] = fmaf(a.x, w.w, acc[0][3]);
            acc[1][0] = fmaf(a.y, w.x, acc[1][0]);
            acc[1][1] = fmaf(a.y, w.y, acc[1][1]);
            acc[1][2] = fmaf(a.y, w.z, acc[1][2]);
            acc[1][3] = fmaf(a.y, w.w, acc[1][3]);
            acc[2][0] = fmaf(a.z, w.x, acc[2][0]);
            acc[2][1] = fmaf(a.z, w.y, acc[2][1]);
            acc[2][2] = fmaf(a.z, w.z, acc[2][2]);
            acc[2][3] = fmaf(a.z, w.w, acc[2][3]);
            acc[3][0] = fmaf(a.w, w.x, acc[3][0]);
            acc[3][1] = fmaf(a.w, w.y, acc[3][1]);
            acc[3][2] = fmaf(a.w, w.z, acc[3][2]);
            acc[3][3] = fmaf(a.w, w.w, acc[3][3]);
        }
    }
    float bb[4] = {0.f, 0.f, 0.f, 0.f};
    #pragma unroll
    for (int j = 0; j < 4; ++j) {
        int col = bn + tx * 4 + j;
        if (col < N) {
            float v = 0.f;
            if (bias1) v += bias1[col];
            if (bias2) v += bias2[col];
            bb[j] = v;
        }
    }
    #pragma unroll
    for (int i = 0; i < 4; ++i) {
        int row = bm + ty * 4 + i;
        #pragma unroll
        for (int j = 0; j < 4; ++j) {
            int col = bn + tx * 4 + j;
            if (col >= N) continue;
            float v = acc[i][j] + bb[j];
            if (mode == 2) v = fast_tanh(v);
            if (mode == 0) {
                ((float*)Cout)[(size_t)row * N + col] = v;
            } else if (mode == 3) {
                int b = row & 31, t = row >> 5;
                ((float*)Cout)[((size_t)b * 1024 + t) * (size_t)N + col] = v;
            } else {
                ((bf16u*)Cout)[(size_t)row * N + col] = f2bf(v);
            }
        }
    }
}

// ---------------------------------------------------------------------------
// Grid-wide spin barrier (monotonic counter, no reset). 64 blocks << capacity
// -> co-residency guaranteed.
// ---------------------------------------------------------------------------
__device__ __forceinline__ void grid_sync(int* ctr, int target) {
    __threadfence();
    __syncthreads();
    if (threadIdx.x == 0) {
        __hip_atomic_fetch_add(ctr, 1, __ATOMIC_RELEASE, __HIP_MEMORY_SCOPE_AGENT);
        while (__hip_atomic_load(ctr, __ATOMIC_ACQUIRE, __HIP_MEMORY_SCOPE_AGENT) < target)
            __builtin_amdgcn_s_sleep(1);
    }
    __syncthreads();
    __threadfence();
}

// ---------------------------------------------------------------------------
// LSTM, one 128-step time chunk. 64 blocks x 256 threads; block owns h-dims
// j0..j0+5 (24 gate rows), Whh slice in LDS. h via hT[2][384][32] (fp32, ws),
// c via cbuf (fp32, ws). gx = x@Wih^T+bih+bhh precomputed for this chunk,
// rows (tl*32+b). y written bf16 at rows (t*32+b).
// ---------------------------------------------------------------------------
__global__ void __launch_bounds__(256) lstm_chunk_kernel(
    const float* __restrict__ gx, const float* __restrict__ Whh,
    const float* __restrict__ h0, const float* __restrict__ c0,
    bf16u* __restrict__ y, float* __restrict__ hT, float* __restrict__ cbuf,
    int* ctr, int t0, int is_first, int is_last,
    float* __restrict__ hs_out, float* __restrict__ cs_out)
{
    const int tid = threadIdx.x;
    const int bid = blockIdx.x;
    const int j0 = bid * 6;
    __shared__ float w_s[24][384];
    __shared__ float gates_s[24 * 32];

    for (int i = tid; i < 24 * 384; i += 256) {
        int r = i / 384, k = i - r * 384;
        int g = r / 6, jj = r - g * 6;
        w_s[r][k] = Whh[(size_t)(g * 384 + j0 + jj) * 384 + k];
    }
    if (is_first) {
        for (int i = tid; i < 6 * 32; i += 256) {
            int jj = i >> 5, b = i & 31;
            hT[(j0 + jj) * 32 + b] = h0[b * 384 + j0 + jj];
        }
    }
    const int ub = tid & 31, ujj = tid >> 5;   // update mapping (tid<192)
    float c_reg = 0.f, h_last = 0.f;
    if (tid < 192)
        c_reg = is_first ? c0[ub * 384 + j0 + ujj] : cbuf[ub * 384 + j0 + ujj];

    grid_sync(ctr, 64);

    const int b = tid & 31, r0 = tid >> 5;     // dot mapping: rows r0,+8,+16
    for (int tl = 0; tl < 128; ++tl) {
        const int t = t0 + tl;
        const float* hR = hT + (t & 1) * (384 * 32);
        float* hW = hT + ((t + 1) & 1) * (384 * 32);
        float s0 = 0.f, s1 = 0.f, s2 = 0.f;
        #pragma unroll 8
        for (int k = 0; k < 384; ++k) {
            float hv = hR[k * 32 + b];
            s0 = fmaf(w_s[r0][k], hv, s0);
            s1 = fmaf(w_s[r0 + 8][k], hv, s1);
            s2 = fmaf(w_s[r0 + 16][k], hv, s2);
        }
        const float* gxrow = gx + ((size_t)tl * 32 + b) * 1536;
        {
            int r = r0;      int g = r / 6, jj = r - g * 6;
            gates_s[r * 32 + b] = s0 + gxrow[g * 384 + j0 + jj];
            r = r0 + 8;      g = r / 6; jj = r - g * 6;
            gates_s[r * 32 + b] = s1 + gxrow[g * 384 + j0 + jj];
            r = r0 + 16;     g = r / 6; jj = r - g * 6;
            gates_s[r * 32 + b] = s2 + gxrow[g * 384 + j0 + jj];
        }
        __syncthreads();
        if (tid < 192) {
            float gi = gates_s[(0 + ujj) * 32 + ub];
            float gf = gates_s[(6 + ujj) * 32 + ub];
            float gg = gates_s[(12 + ujj) * 32 + ub];
            float go = gates_s[(18 + ujj) * 32 + ub];
            c_reg = sigmoidf(gf) * c_reg + sigmoidf(gi) * fast_tanh(gg);
            float hv = sigmoidf(go) * fast_tanh(c_reg);
            h_last = hv;
            hW[(j0 + ujj) * 32 + ub] = hv;
            y[((size_t)t * 32 + ub) * 384 + j0 + ujj] = f2bf(hv);
        }
        grid_sync(ctr, 64 * (tl + 2));
    }
    if (tid < 192) {
        cbuf[ub * 384 + j0 + ujj] = c_reg;
        if (is_last) {
            hs_out[ub * 384 + j0 + ujj] = h_last;
            cs_out[ub * 384 + j0 + ujj] = c_reg;
        }
    }
}

// ---------------------------------------------------------------------------
// Causal flash attention, bf16 in/out. Block = (q-tile 32, batch). 256 thr.
// Rows at rt=(pos*32+b). Online softmax, fp32 accumulation.
// ---------------------------------------------------------------------------
__global__ void __launch_bounds__(256) attn_kernel(
    const bf16u* __restrict__ outy, const bf16u* __restrict__ keys,
    bf16u* __restrict__ ctxv)
{
    const int b = blockIdx.y;
    const int q0 = blockIdx.x * 32;
    const int tid = threadIdx.x;
    __shared__ uint32 Qs[32][194];
    __shared__ uint32 Ks[16][194];
    __shared__ uint32 Vs[16][192];
    __shared__ float Ss[32][16];
    __shared__ float m_s[32], l_s[32], alpha_s[32];

    for (int i = tid; i < 32 * 192; i += 256) {
        int q = i / 192, dp = i - q * 192;
        Qs[q][dp] = ((const uint32*)(outy + ((size_t)(q0 + q) * 32 + b) * 384))[dp];
    }
    if (tid < 32) { m_s[tid] = -3e38f; l_s[tid] = 0.f; }

    const int qo = tid >> 3, dg = tid & 7;
    float O[48];
    #pragma unroll
    for (int d = 0; d < 48; ++d) O[d] = 0.f;

    const int nkt = (q0 + 32) >> 4;
    for (int kt = 0; kt < nkt; ++kt) {
        const int k0 = kt * 16;
        __syncthreads();
        for (int i = tid; i < 16 * 192; i += 256) {
            int kk = i / 192, dp = i - kk * 192;
            size_t rt = (size_t)(k0 + kk) * 32 + b;
            Ks[kk][dp] = ((const uint32*)(keys + rt * 384))[dp];
            Vs[kk][dp] = ((const uint32*)(outy + rt * 384))[dp];
        }
        __syncthreads();
        #pragma unroll
        for (int pp = 0; pp < 2; ++pp) {
            int p = tid + pp * 256;
            int q = p >> 4, k = p & 15;
            const uint32* qrow = Qs[q];
            const uint32* krow = Ks[k];
            float acc = 0.f;
            for (int dp = 0; dp < 192; ++dp) {
                uint32 qa = qrow[dp], ka = krow[dp];
                acc = fmaf(bflo(qa), bflo(ka), acc);
                acc = fmaf(bfhi(qa), bfhi(ka), acc);
            }
            acc *= 0.051031036307982884f;    // 1/sqrt(384)
            Ss[q][k] = ((k0 + k) <= (q0 + q)) ? acc : -1e30f;
        }
        __syncthreads();
        if (tid < 32) {
            int q = tid;
            float mt = m_s[q];
            #pragma unroll
            for (int k = 0; k < 16; ++k) mt = fmaxf(mt, Ss[q][k]);
            float alpha = __expf(m_s[q] - mt);
            float l = l_s[q] * alpha;
            #pragma unroll
            for (int k = 0; k < 16; ++k) {
                float pv = __expf(Ss[q][k] - mt);
                Ss[q][k] = pv;
                l += pv;
            }
            m_s[q] = mt; l_s[q] = l; alpha_s[q] = alpha;
        }
        __syncthreads();
        {
            float al = alpha_s[qo];
            #pragma unroll
            for (int d = 0; d < 48; ++d) O[d] *= al;
            for (int k = 0; k < 16; ++k) {
                float pv = Ss[qo][k];
                const uint32* vrow = Vs[k] + dg * 24;
                #pragma unroll
                for (int dp = 0; dp < 24; ++dp) {
                    uint32 va = vrow[dp];
                    O[2 * dp]     = fmaf(pv, bflo(va), O[2 * dp]);
                    O[2 * dp + 1] = fmaf(pv, bfhi(va), O[2 * dp + 1]);
                }
            }
        }
    }
    float inv = 1.f / l_s[qo];
    uint32* dst = (uint32*)(ctxv + ((size_t)(q0 + qo) * 32 + b) * 384) + dg * 24;
    #pragma unroll
    for (int dp = 0; dp < 24; ++dp)
        dst[dp] = pack2bf(O[2 * dp] * inv, O[2 * dp + 1] * inv);
}

// ---------------------------------------------------------------------------
extern "C" void kernel_launch(void* const* d_in, const int* in_sizes, int n_in,
                              void* d_out, int out_size, void* d_ws, size_t ws_size,
                              hipStream_t stream) {
    (void)in_sizes; (void)n_in; (void)out_size; (void)ws_size;
    const int*   x        = (const int*)d_in[0];
    const float* context  = (const float*)d_in[1];
    const float* h_in     = (const float*)d_in[2];
    const float* c_in     = (const float*)d_in[3];
    const float* emb      = (const float*)d_in[4];
    const float* ctx_W    = (const float*)d_in[5];
    const float* ctx_b    = (const float*)d_in[6];
    const float* Wih0     = (const float*)d_in[7];
    const float* Wih_rest = (const float*)d_in[8];
    const float* Whh      = (const float*)d_in[9];
    const float* bih      = (const float*)d_in[10];
    const float* bhh      = (const float*)d_in[11];
    const float* Wa       = (const float*)d_in[12];
    const float* comb_W   = (const float*)d_in[13];
    const float* comb_b   = (const float*)d_in[14];
    const float* fc_W     = (const float*)d_in[15];
    const float* fc_b     = (const float*)d_in[16];
    float* out = (float*)d_out;

    // ---- workspace layout, 92.4 MB total ----
    char* wsb = (char*)d_ws;
    int*   ctr  = (int*)(wsb + 0);                    //   1 KB (32 counters)
    float* hT   = (float*)(wsb + 1024);               //  96 KB [2][384][32]
    float* cbuf = (float*)(wsb + 99328);              //  48 KB [32][384]
    bf16u* inp  = (bf16u*)(wsb + 148480);             //  16.78 MB [32768,256]
    bf16u* yA   = (bf16u*)(wsb + 16925696ull);        //  25.17 MB [32768,384]
    bf16u* yB   = (bf16u*)(wsb + 42091520ull);        //  25.17 MB [32768,384]
    float* gxf  = (float*)(wsb + 67257344ull);        //  25.17 MB [4096,1536]
    bf16u* keysu = (bf16u*)gxf;                       // reuse after LSTM stack
    bf16u* ctxvu = yA;                                // reuse (layer-2 y dead)
    bf16u* combu = (bf16u*)gxf;                       // reuse after attention

    hipMemsetAsync(d_ws, 0, 1024, stream);            // zero barrier counters

    embed_ctx_kernel<<<2048, 128, 0, stream>>>(x, context, emb, ctx_W, ctx_b, inp);

    const size_t HS_OFF = (size_t)32768 * 100;
    for (int l = 0; l < 4; ++l) {
        const int K = l ? 384 : 256;
        const float* Wl = l ? (Wih_rest + (size_t)(l - 1) * 1536 * 384) : Wih0;
        const bf16u* Ain = (l == 0) ? inp : ((l == 1 || l == 3) ? yA : yB);
        bf16u* yl = (l & 1) ? yB : yA;
        for (int c = 0; c < 8; ++c) {
            gemm_kernel<<<dim3(24, 64), 256, 0, stream>>>(
                Ain + (size_t)c * 4096 * K, nullptr, K, Wl,
                bih + l * 1536, bhh + l * 1536, gxf, 4096, 1536, K, 0);
            lstm_chunk_kernel<<<64, 256, 0, stream>>>(
                gxf, Whh + (size_t)l * 1536 * 384,
                h_in + l * 12288, c_in + l * 12288,
                yl, hT, cbuf, ctr + (l * 8 + c), c * 128,
                c == 0, c == 7,
                out + HS_OFF + l * 12288, out + HS_OFF + 49152 + l * 12288);
        }
    }
    // keys = y3 @ Wa^T  (yB -> gx region, bf16)
    gemm_kernel<<<dim3(6, 512), 256, 0, stream>>>(
        yB, nullptr, 384, Wa, nullptr, nullptr, keysu, 32768, 384, 384, 1);
    // ctx_vec (flash attention)  (yB, keys -> yA region)
    attn_kernel<<<dim3(32, 32), 256, 0, stream>>>(yB, keysu, ctxvu);
    // combined = tanh([y3, ctx] @ comb_W^T + b)  (-> gx region, bf16)
    gemm_kernel<<<dim3(6, 512), 256, 0, stream>>>(
        yB, ctxvu, 384, comb_W, comb_b, nullptr, combu, 32768, 384, 768, 2);
    // logits = combined @ fc_W^T + fc_b  (-> d_out, permuted to [b][t][100])
    gemm_kernel<<<dim3(2, 512), 256, 0, stream>>>(
        combu, nullptr, 384, fc_W, fc_b, nullptr, out, 32768, 100, 384, 3);
}

// Round 3
// 42902.005 us; speedup vs baseline: 2.5375x; 2.5375x over previous
//
#include <hip/hip_runtime.h>

typedef unsigned int  uint32;
typedef unsigned long long u64;
typedef unsigned short bf16u;
typedef __attribute__((ext_vector_type(8))) short s8v;    // 8 bf16 (4 VGPRs)
typedef __attribute__((ext_vector_type(4))) float f4v;    // MFMA acc

__device__ __forceinline__ float fast_tanh(float x) {
    x = fminf(9.f, fmaxf(-9.f, x));
    float e = __expf(2.f * x);
    return (e - 1.f) / (e + 1.f);
}
__device__ __forceinline__ float sigmoidf(float x) {
    return 1.f / (1.f + __expf(-x));
}
__device__ __forceinline__ bf16u f2bf(float f) {
    uint32 u = __float_as_uint(f);
    u += 0x7fffu + ((u >> 16) & 1u);
    return (bf16u)(u >> 16);
}
__device__ __forceinline__ float bf2f(bf16u u) {
    return __uint_as_float(((uint32)u) << 16);
}
__device__ __forceinline__ uint32 pack2bf(float lo, float hi) {
    return (uint32)f2bf(lo) | ((uint32)f2bf(hi) << 16);
}
__device__ __forceinline__ float bflo(uint32 p) { return __uint_as_float(p << 16); }
__device__ __forceinline__ float bfhi(uint32 p) { return __uint_as_float(p & 0xffff0000u); }

// ---------------------------------------------------------------------------
// Embedding + context projection -> inp [rt=t*32+b][256] bf16 (emb || ctx)
// ---------------------------------------------------------------------------
__global__ void __launch_bounds__(128) embed_ctx_kernel(
    const int* __restrict__ x, const float* __restrict__ ctx,
    const float* __restrict__ emb, const float* __restrict__ ctxW,
    const float* __restrict__ ctxb, bf16u* __restrict__ inp)
{
    const int r0 = blockIdx.x * 16;
    const int tid = threadIdx.x;
    __shared__ float cs[16][301];
    __shared__ int xs[16];
    for (int i = tid; i < 16 * 300; i += 128) {
        int row = i / 300, k = i - row * 300;
        int rt = r0 + row, b = rt & 31, t = rt >> 5;
        cs[row][k] = ctx[((size_t)b * 1024 + t) * 300 + k];
    }
    if (tid < 16) {
        int rt = r0 + tid;
        xs[tid] = x[(rt & 31) * 1024 + (rt >> 5)];
    }
    __syncthreads();
    float acc[16];
    #pragma unroll
    for (int row = 0; row < 16; ++row) acc[row] = 0.f;
    for (int k = 0; k < 300; ++k) {
        float w = ctxW[tid * 300 + k];
        #pragma unroll
        for (int row = 0; row < 16; ++row) acc[row] = fmaf(w, cs[row][k], acc[row]);
    }
    float bb = ctxb[tid];
    for (int row = 0; row < 16; ++row) {
        size_t base = (size_t)(r0 + row) * 256;
        inp[base + tid]       = f2bf(emb[xs[row] * 128 + tid]);
        inp[base + 128 + tid] = f2bf(acc[row] + bb);
    }
}

// ---------------------------------------------------------------------------
// GEMM: C[M,N] = A[M,K](bf16) @ W[N,K]^T(f32) (+bias1+bias2)
// mode 0: f32 out TRANSPOSED -> Cout[col*ldc + row]  (for gxT)
// mode 1: bf16 out; mode 2: bf16+tanh; mode 3: f32 out, row rt->(b*1024+t).
// ---------------------------------------------------------------------------
__global__ void __launch_bounds__(256) gemm_kernel(
    const bf16u* __restrict__ A0, const bf16u* __restrict__ A1, int K0,
    const float* __restrict__ W, const float* __restrict__ bias1,
    const float* __restrict__ bias2, void* __restrict__ Cout,
    int M, int N, int K, int mode, int ldc)
{
    __shared__ float As[16][68];
    __shared__ float Ws[16][68];
    const int tid = threadIdx.x;
    const int bn = blockIdx.x * 64, bm = blockIdx.y * 64;
    const int tx = tid & 15, ty = tid >> 4;
    const int loadRow = tid >> 2, loadK4 = (tid & 3) * 4;
    float acc[4][4] = {};
    for (int k0 = 0; k0 < K; k0 += 16) {
        const bf16u* Ab; int kb, lda;
        if (k0 < K0) { Ab = A0; kb = k0; lda = K0; }
        else         { Ab = A1; kb = k0 - K0; lda = K - K0; }
        ushort4 av = *(const ushort4*)(Ab + (size_t)(bm + loadRow) * lda + kb + loadK4);
        float4 wv = make_float4(0.f, 0.f, 0.f, 0.f);
        int wrow = bn + loadRow;
        if (wrow < N) wv = *(const float4*)(W + (size_t)wrow * K + k0 + loadK4);
        __syncthreads();
        As[loadK4 + 0][loadRow] = bf2f(av.x);
        As[loadK4 + 1][loadRow] = bf2f(av.y);
        As[loadK4 + 2][loadRow] = bf2f(av.z);
        As[loadK4 + 3][loadRow] = bf2f(av.w);
        Ws[loadK4 + 0][loadRow] = wv.x;
        Ws[loadK4 + 1][loadRow] = wv.y;
        Ws[loadK4 + 2][loadRow] = wv.z;
        Ws[loadK4 + 3][loadRow] = wv.w;
        __syncthreads();
        #pragma unroll
        for (int kk = 0; kk < 16; ++kk) {
            float4 a = *(const float4*)&As[kk][ty * 4];
            float4 w = *(const float4*)&Ws[kk][tx * 4];
            acc[0][0] = fmaf(a.x, w.x, acc[0][0]);
            acc[0][1] = fmaf(a.x, w.y, acc[0][1]);
            acc[0][2] = fmaf(a.x, w.z, acc[0][2]);
            acc[0][3] = fmaf(a.x, w.w, acc[0][3]);
            acc[1][0] = fmaf(a.y, w.x, acc[1][0]);
            acc[1][1] = fmaf(a.y, w.y, acc[1][1]);
            acc[1][2] = fmaf(a.y, w.z, acc[1][2]);
            acc[1][3] = fmaf(a.y, w.w, acc[1][3]);
            acc[2][0] = fmaf(a.z, w.x, acc[2][0]);
            acc[2][1] = fmaf(a.z, w.y, acc[2][1]);
            acc[2][2] = fmaf(a.z, w.z, acc[2][2]);
            acc[2][3] = fmaf(a.z, w.w, acc[2][3]);
            acc[3][0] = fmaf(a.w, w.x, acc[3][0]);
            acc[3][1] = fmaf(a.w, w.y, acc[3][1]);
            acc[3][2] = fmaf(a.w, w.z, acc[3][2]);
            acc[3][3] = fmaf(a.w, w.w, acc[3][3]);
        }
    }
    float bb[4] = {0.f, 0.f, 0.f, 0.f};
    #pragma unroll
    for (int j = 0; j < 4; ++j) {
        int col = bn + tx * 4 + j;
        if (col < N) {
            float v = 0.f;
            if (bias1) v += bias1[col];
            if (bias2) v += bias2[col];
            bb[j] = v;
        }
    }
    #pragma unroll
    for (int i = 0; i < 4; ++i) {
        int row = bm + ty * 4 + i;
        #pragma unroll
        for (int j = 0; j < 4; ++j) {
            int col = bn + tx * 4 + j;
            if (col >= N) continue;
            float v = acc[i][j] + bb[j];
            if (mode == 2) v = fast_tanh(v);
            if (mode == 0) {
                ((float*)Cout)[(size_t)col * ldc + row] = v;
            } else if (mode == 3) {
                int b = row & 31, t = row >> 5;
                ((float*)Cout)[((size_t)b * 1024 + t) * (size_t)N + col] = v;
            } else {
                ((bf16u*)Cout)[(size_t)row * N + col] = f2bf(v);
            }
        }
    }
}

// ---------------------------------------------------------------------------
// LSTM, one 128-step chunk. 48 blocks x 256 threads. Block owns 8 hidden dims
// (all 4 gates = 32 gate rows). Whh slice lives in REGISTERS as hi/lo bf16
// MFMA B-fragments; h broadcast via hbuf[2][32][384] (u32 = hi|lo bf16) using
// relaxed AGENT-scope atomics (sc0sc1, L3-coherent, NO cache-flushing fences).
// Per step: stage h -> LDS (coalesced), 36 MFMAs, block-local cell update.
// ---------------------------------------------------------------------------
__global__ void __launch_bounds__(256) lstm_chunk_kernel(
    const float* __restrict__ gxT,   // [1536][4096] fp32 (chunk, row=tl*32+b)
    const float* __restrict__ Whh,   // [1536][384] fp32
    const float* __restrict__ h0, const float* __restrict__ c0,
    bf16u* __restrict__ y,           // [t*32+b][384] bf16
    uint32* __restrict__ hbuf,       // [2][32][384] u32 packed hi|lo
    float* __restrict__ cbuf, int* __restrict__ ctr,
    int t0, int is_first, int is_last,
    float* __restrict__ hs_out, float* __restrict__ cs_out)
{
    const int tid = threadIdx.x, bid = blockIdx.x;
    const int j0 = bid * 8;
    const int wave = tid >> 6, lane = tid & 63;
    const int ntile = wave & 1, mtile = wave >> 1;
    const int ncol = lane & 15, quad = lane >> 4;
    const int n = ntile * 16 + ncol;            // local gate-row 0..31
    const int gsel = n >> 3, jl_n = n & 7;
    const int wrow = gsel * 384 + j0 + jl_n;    // Whh row for B-frag
    const int Mrow = mtile * 16 + ncol;         // batch row for A-frag
    const int ub = tid & 31, ujj = tid >> 5;    // update mapping (b, j-local)
    const int jglob = j0 + ujj;

    __shared__ __align__(16) uint32 h_hi[32][192];   // bf16-pair planes
    __shared__ __align__(16) uint32 h_lo[32][192];
    __shared__ float gates_s[32][33];

    // ---- B fragments: Whh rows split hi/lo bf16 (once per launch) ----
    s8v Bhi[12], Blo[12];
    #pragma unroll
    for (int kt = 0; kt < 12; ++kt) {
        const float* wp = Whh + (size_t)wrow * 384 + kt * 32 + quad * 8;
        s8v hi, lo;
        #pragma unroll
        for (int j = 0; j < 8; ++j) {
            float w = wp[j];
            bf16u wh = f2bf(w);
            bf16u wl = f2bf(w - bf2f(wh));
            hi[j] = (short)wh; lo[j] = (short)wl;
        }
        Bhi[kt] = hi; Blo[kt] = lo;
    }

    float c_reg, h_last = 0.f;
    if (is_first) {
        float hv = h0[ub * 384 + jglob];
        bf16u hh = f2bf(hv);
        bf16u hl = f2bf(hv - bf2f(hh));
        __hip_atomic_store(&hbuf[ub * 384 + jglob],
                           (uint32)hh | ((uint32)hl << 16),
                           __ATOMIC_RELAXED, __HIP_MEMORY_SCOPE_AGENT);
        c_reg = c0[ub * 384 + jglob];
    } else {
        c_reg = cbuf[ub * 384 + jglob];
    }
    __syncthreads();                 // drains vmcnt -> stores at coherence pt
    if (tid == 0) {
        __hip_atomic_fetch_add(ctr, 1, __ATOMIC_RELAXED, __HIP_MEMORY_SCOPE_AGENT);
        while (__hip_atomic_load(ctr, __ATOMIC_RELAXED, __HIP_MEMORY_SCOPE_AGENT) < 48)
            __builtin_amdgcn_s_sleep(1);
    }
    __syncthreads();

    for (int tl = 0; tl < 128; ++tl) {
        const int t = t0 + tl;
        uint32* hR = hbuf + (t & 1) * (32 * 384);
        uint32* hW = hbuf + ((t + 1) & 1) * (32 * 384);

        // prefetch gx for this thread's update role (L2-cached, coalesced)
        float gxv[4];
        #pragma unroll
        for (int g = 0; g < 4; ++g)
            gxv[g] = gxT[(size_t)(g * 384 + jglob) * 4096 + tl * 32 + ub];

        // ---- stage h into LDS (coalesced coherent loads, unpack hi/lo) ----
        #pragma unroll
        for (int w = 0; w < 24; ++w) {
            int l = tid + w * 256;               // u64 index, 6144 total
            int m = l / 192, rem = l - m * 192;  // row, k-pair index
            u64 v = __hip_atomic_load((u64*)hR + l,
                                      __ATOMIC_RELAXED, __HIP_MEMORY_SCOPE_AGENT);
            uint32 v0 = (uint32)v, v1 = (uint32)(v >> 32);
            h_hi[m][rem] = (v0 & 0xffffu) | (v1 << 16);
            h_lo[m][rem] = (v0 >> 16) | (v1 & 0xffff0000u);
        }
        __syncthreads();

        // ---- MFMA: D[32b x 32rows] = h x Whh^T (hi/lo split, fp32 acc) ----
        f4v acc = {0.f, 0.f, 0.f, 0.f};
        #pragma unroll
        for (int kt = 0; kt < 12; ++kt) {
            s8v ahi = *(const s8v*)&h_hi[Mrow][kt * 16 + quad * 4];
            s8v alo = *(const s8v*)&h_lo[Mrow][kt * 16 + quad * 4];
            acc = __builtin_amdgcn_mfma_f32_16x16x32_bf16(ahi, Bhi[kt], acc, 0, 0, 0);
            acc = __builtin_amdgcn_mfma_f32_16x16x32_bf16(alo, Bhi[kt], acc, 0, 0, 0);
            acc = __builtin_amdgcn_mfma_f32_16x16x32_bf16(ahi, Blo[kt], acc, 0, 0, 0);
        }
        #pragma unroll
        for (int r = 0; r < 4; ++r)
            gates_s[n][mtile * 16 + quad * 4 + r] = acc[r];
        __syncthreads();

        // ---- cell update (block-local: all 4 gates of jglob are here) ----
        float pre_i = gates_s[ujj][ub]      + gxv[0];
        float pre_f = gates_s[8 + ujj][ub]  + gxv[1];
        float pre_g = gates_s[16 + ujj][ub] + gxv[2];
        float pre_o = gates_s[24 + ujj][ub] + gxv[3];
        c_reg = sigmoidf(pre_f) * c_reg + sigmoidf(pre_i) * fast_tanh(pre_g);
        float hv = sigmoidf(pre_o) * fast_tanh(c_reg);
        h_last = hv;
        bf16u hh = f2bf(hv);
        bf16u hl = f2bf(hv - bf2f(hh));
        __hip_atomic_store(&hW[ub * 384 + jglob],
                           (uint32)hh | ((uint32)hl << 16),
                           __ATOMIC_RELAXED, __HIP_MEMORY_SCOPE_AGENT);
        y[((size_t)t * 32 + ub) * 384 + jglob] = hh;

        __syncthreads();             // drain h stores + protect LDS reuse
        if (tid == 0) {
            __hip_atomic_fetch_add(ctr, 1, __ATOMIC_RELAXED, __HIP_MEMORY_SCOPE_AGENT);
            int tgt = 48 * (tl + 2);
            while (__hip_atomic_load(ctr, __ATOMIC_RELAXED, __HIP_MEMORY_SCOPE_AGENT) < tgt)
                __builtin_amdgcn_s_sleep(1);
        }
        __syncthreads();
    }

    cbuf[ub * 384 + jglob] = c_reg;
    if (is_last) {
        hs_out[ub * 384 + jglob] = h_last;
        cs_out[ub * 384 + jglob] = c_reg;
    }
}

// ---------------------------------------------------------------------------
// Causal flash attention, bf16 in/out (unchanged from passing round).
// ---------------------------------------------------------------------------
__global__ void __launch_bounds__(256) attn_kernel(
    const bf16u* __restrict__ outy, const bf16u* __restrict__ keys,
    bf16u* __restrict__ ctxv)
{
    const int b = blockIdx.y;
    const int q0 = blockIdx.x * 32;
    const int tid = threadIdx.x;
    __shared__ uint32 Qs[32][194];
    __shared__ uint32 Ks[16][194];
    __shared__ uint32 Vs[16][192];
    __shared__ float Ss[32][16];
    __shared__ float m_s[32], l_s[32], alpha_s[32];

    for (int i = tid; i < 32 * 192; i += 256) {
        int q = i / 192, dp = i - q * 192;
        Qs[q][dp] = ((const uint32*)(outy + ((size_t)(q0 + q) * 32 + b) * 384))[dp];
    }
    if (tid < 32) { m_s[tid] = -3e38f; l_s[tid] = 0.f; }

    const int qo = tid >> 3, dg = tid & 7;
    float O[48];
    #pragma unroll
    for (int d = 0; d < 48; ++d) O[d] = 0.f;

    const int nkt = (q0 + 32) >> 4;
    for (int kt = 0; kt < nkt; ++kt) {
        const int k0 = kt * 16;
        __syncthreads();
        for (int i = tid; i < 16 * 192; i += 256) {
            int kk = i / 192, dp = i - kk * 192;
            size_t rt = (size_t)(k0 + kk) * 32 + b;
            Ks[kk][dp] = ((const uint32*)(keys + rt * 384))[dp];
            Vs[kk][dp] = ((const uint32*)(outy + rt * 384))[dp];
        }
        __syncthreads();
        #pragma unroll
        for (int pp = 0; pp < 2; ++pp) {
            int p = tid + pp * 256;
            int q = p >> 4, k = p & 15;
            const uint32* qrow = Qs[q];
            const uint32* krow = Ks[k];
            float acc = 0.f;
            for (int dp = 0; dp < 192; ++dp) {
                uint32 qa = qrow[dp], ka = krow[dp];
                acc = fmaf(bflo(qa), bflo(ka), acc);
                acc = fmaf(bfhi(qa), bfhi(ka), acc);
            }
            acc *= 0.051031036307982884f;    // 1/sqrt(384)
            Ss[q][k] = ((k0 + k) <= (q0 + q)) ? acc : -1e30f;
        }
        __syncthreads();
        if (tid < 32) {
            int q = tid;
            float mt = m_s[q];
            #pragma unroll
            for (int k = 0; k < 16; ++k) mt = fmaxf(mt, Ss[q][k]);
            float alpha = __expf(m_s[q] - mt);
            float l = l_s[q] * alpha;
            #pragma unroll
            for (int k = 0; k < 16; ++k) {
                float pv = __expf(Ss[q][k] - mt);
                Ss[q][k] = pv;
                l += pv;
            }
            m_s[q] = mt; l_s[q] = l; alpha_s[q] = alpha;
        }
        __syncthreads();
        {
            float al = alpha_s[qo];
            #pragma unroll
            for (int d = 0; d < 48; ++d) O[d] *= al;
            for (int k = 0; k < 16; ++k) {
                float pv = Ss[qo][k];
                const uint32* vrow = Vs[k] + dg * 24;
                #pragma unroll
                for (int dp = 0; dp < 24; ++dp) {
                    uint32 va = vrow[dp];
                    O[2 * dp]     = fmaf(pv, bflo(va), O[2 * dp]);
                    O[2 * dp + 1] = fmaf(pv, bfhi(va), O[2 * dp + 1]);
                }
            }
        }
    }
    float inv = 1.f / l_s[qo];
    uint32* dst = (uint32*)(ctxv + ((size_t)(q0 + qo) * 32 + b) * 384) + dg * 24;
    #pragma unroll
    for (int dp = 0; dp < 24; ++dp)
        dst[dp] = pack2bf(O[2 * dp] * inv, O[2 * dp + 1] * inv);
}

// ---------------------------------------------------------------------------
extern "C" void kernel_launch(void* const* d_in, const int* in_sizes, int n_in,
                              void* d_out, int out_size, void* d_ws, size_t ws_size,
                              hipStream_t stream) {
    (void)in_sizes; (void)n_in; (void)out_size; (void)ws_size;
    const int*   x        = (const int*)d_in[0];
    const float* context  = (const float*)d_in[1];
    const float* h_in     = (const float*)d_in[2];
    const float* c_in     = (const float*)d_in[3];
    const float* emb      = (const float*)d_in[4];
    const float* ctx_W    = (const float*)d_in[5];
    const float* ctx_b    = (const float*)d_in[6];
    const float* Wih0     = (const float*)d_in[7];
    const float* Wih_rest = (const float*)d_in[8];
    const float* Whh      = (const float*)d_in[9];
    const float* bih      = (const float*)d_in[10];
    const float* bhh      = (const float*)d_in[11];
    const float* Wa       = (const float*)d_in[12];
    const float* comb_W   = (const float*)d_in[13];
    const float* comb_b   = (const float*)d_in[14];
    const float* fc_W     = (const float*)d_in[15];
    const float* fc_b     = (const float*)d_in[16];
    float* out = (float*)d_out;

    // ---- workspace layout ----
    char* wsb = (char*)d_ws;
    int*    ctr  = (int*)(wsb + 0);                   //   1 KB (32 counters)
    uint32* hbuf = (uint32*)(wsb + 1024);             //  96 KB [2][32][384]
    float*  cbuf = (float*)(wsb + 99328);             //  48 KB [32][384]
    bf16u*  inp  = (bf16u*)(wsb + 148480);            //  16.78 MB [32768,256]
    bf16u*  yA   = (bf16u*)(wsb + 16925696ull);       //  25.17 MB [32768,384]
    bf16u*  yB   = (bf16u*)(wsb + 42091520ull);       //  25.17 MB [32768,384]
    float*  gxT  = (float*)(wsb + 67257344ull);       //  25.17 MB [1536,4096]
    bf16u* keysu = (bf16u*)gxT;                       // reuse after LSTM stack
    bf16u* ctxvu = yA;                                // reuse (layer-2 y dead)
    bf16u* combu = (bf16u*)gxT;                       // reuse after attention

    hipMemsetAsync(d_ws, 0, 1024, stream);            // zero barrier counters

    embed_ctx_kernel<<<2048, 128, 0, stream>>>(x, context, emb, ctx_W, ctx_b, inp);

    const size_t HS_OFF = (size_t)32768 * 100;
    for (int l = 0; l < 4; ++l) {
        const int K = l ? 384 : 256;
        const float* Wl = l ? (Wih_rest + (size_t)(l - 1) * 1536 * 384) : Wih0;
        const bf16u* Ain = (l == 0) ? inp : ((l == 1 || l == 3) ? yA : yB);
        bf16u* yl = (l & 1) ? yB : yA;
        for (int c = 0; c < 8; ++c) {
            gemm_kernel<<<dim3(24, 64), 256, 0, stream>>>(
                Ain + (size_t)c * 4096 * K, nullptr, K, Wl,
                bih + l * 1536, bhh + l * 1536, gxT, 4096, 1536, K, 0, 4096);
            lstm_chunk_kernel<<<48, 256, 0, stream>>>(
                gxT, Whh + (size_t)l * 1536 * 384,
                h_in + l * 12288, c_in + l * 12288,
                yl, hbuf, cbuf, ctr + (l * 8 + c), c * 128,
                c == 0, c == 7,
                out + HS_OFF + l * 12288, out + HS_OFF + 49152 + l * 12288);
        }
    }
    // keys = y3 @ Wa^T  (yB -> gxT region, bf16)
    gemm_kernel<<<dim3(6, 512), 256, 0, stream>>>(
        yB, nullptr, 384, Wa, nullptr, nullptr, keysu, 32768, 384, 384, 1, 0);
    // ctx_vec (flash attention)  (yB, keys -> yA region)
    attn_kernel<<<dim3(32, 32), 256, 0, stream>>>(yB, keysu, ctxvu);
    // combined = tanh([y3, ctx] @ comb_W^T + b)  (-> gxT region, bf16)
    gemm_kernel<<<dim3(6, 512), 256, 0, stream>>>(
        yB, ctxvu, 384, comb_W, comb_b, nullptr, combu, 32768, 384, 768, 2, 0);
    // logits = combined @ fc_W^T + fc_b  (-> d_out, permuted to [b][t][100])
    gemm_kernel<<<dim3(2, 512), 256, 0, stream>>>(
        combu, nullptr, 384, fc_W, fc_b, nullptr, out, 32768, 100, 384, 3, 0);
}

// Round 4
// 38944.043 us; speedup vs baseline: 2.7954x; 1.1016x over previous
//
#include <hip/hip_runtime.h>

typedef unsigned int  uint32;
typedef unsigned long long u64;
typedef unsigned short bf16u;
typedef __attribute__((ext_vector_type(8))) short s8v;    // 8 bf16 (4 VGPRs)
typedef __attribute__((ext_vector_type(4))) float f4v;    // MFMA acc

__device__ __forceinline__ float fast_tanh(float x) {
    x = fminf(9.f, fmaxf(-9.f, x));
    float e = __expf(2.f * x);
    return (e - 1.f) / (e + 1.f);
}
__device__ __forceinline__ float sigmoidf(float x) {
    return 1.f / (1.f + __expf(-x));
}
__device__ __forceinline__ bf16u f2bf(float f) {
    uint32 u = __float_as_uint(f);
    u += 0x7fffu + ((u >> 16) & 1u);
    return (bf16u)(u >> 16);
}
__device__ __forceinline__ float bf2f(bf16u u) {
    return __uint_as_float(((uint32)u) << 16);
}
__device__ __forceinline__ uint32 pack2bf(float lo, float hi) {
    return (uint32)f2bf(lo) | ((uint32)f2bf(hi) << 16);
}
__device__ __forceinline__ float bflo(uint32 p) { return __uint_as_float(p << 16); }
__device__ __forceinline__ float bfhi(uint32 p) { return __uint_as_float(p & 0xffff0000u); }

// ---------------------------------------------------------------------------
// Embedding + context projection -> inp [rt=t*32+b][256] bf16 (emb || ctx)
// ---------------------------------------------------------------------------
__global__ void __launch_bounds__(128) embed_ctx_kernel(
    const int* __restrict__ x, const float* __restrict__ ctx,
    const float* __restrict__ emb, const float* __restrict__ ctxW,
    const float* __restrict__ ctxb, bf16u* __restrict__ inp)
{
    const int r0 = blockIdx.x * 16;
    const int tid = threadIdx.x;
    __shared__ float cs[16][301];
    __shared__ int xs[16];
    for (int i = tid; i < 16 * 300; i += 128) {
        int row = i / 300, k = i - row * 300;
        int rt = r0 + row, b = rt & 31, t = rt >> 5;
        cs[row][k] = ctx[((size_t)b * 1024 + t) * 300 + k];
    }
    if (tid < 16) {
        int rt = r0 + tid;
        xs[tid] = x[(rt & 31) * 1024 + (rt >> 5)];
    }
    __syncthreads();
    float acc[16];
    #pragma unroll
    for (int row = 0; row < 16; ++row) acc[row] = 0.f;
    for (int k = 0; k < 300; ++k) {
        float w = ctxW[tid * 300 + k];
        #pragma unroll
        for (int row = 0; row < 16; ++row) acc[row] = fmaf(w, cs[row][k], acc[row]);
    }
    float bb = ctxb[tid];
    for (int row = 0; row < 16; ++row) {
        size_t base = (size_t)(r0 + row) * 256;
        inp[base + tid]       = f2bf(emb[xs[row] * 128 + tid]);
        inp[base + 128 + tid] = f2bf(acc[row] + bb);
    }
}

// ---------------------------------------------------------------------------
// GEMM: C[M,N] = A[M,K](bf16) @ W[N,K]^T(f32) (+bias1+bias2)
// mode 0: f32 out TRANSPOSED -> Cout[col*ldc + row]  (for gxT)
// mode 1: bf16 out; mode 2: bf16+tanh; mode 3: f32 out, row rt->(b*1024+t).
// ---------------------------------------------------------------------------
__global__ void __launch_bounds__(256) gemm_kernel(
    const bf16u* __restrict__ A0, const bf16u* __restrict__ A1, int K0,
    const float* __restrict__ W, const float* __restrict__ bias1,
    const float* __restrict__ bias2, void* __restrict__ Cout,
    int M, int N, int K, int mode, int ldc)
{
    __shared__ float As[16][68];
    __shared__ float Ws[16][68];
    const int tid = threadIdx.x;
    const int bn = blockIdx.x * 64, bm = blockIdx.y * 64;
    const int tx = tid & 15, ty = tid >> 4;
    const int loadRow = tid >> 2, loadK4 = (tid & 3) * 4;
    float acc[4][4] = {};
    for (int k0 = 0; k0 < K; k0 += 16) {
        const bf16u* Ab; int kb, lda;
        if (k0 < K0) { Ab = A0; kb = k0; lda = K0; }
        else         { Ab = A1; kb = k0 - K0; lda = K - K0; }
        ushort4 av = *(const ushort4*)(Ab + (size_t)(bm + loadRow) * lda + kb + loadK4);
        float4 wv = make_float4(0.f, 0.f, 0.f, 0.f);
        int wrow = bn + loadRow;
        if (wrow < N) wv = *(const float4*)(W + (size_t)wrow * K + k0 + loadK4);
        __syncthreads();
        As[loadK4 + 0][loadRow] = bf2f(av.x);
        As[loadK4 + 1][loadRow] = bf2f(av.y);
        As[loadK4 + 2][loadRow] = bf2f(av.z);
        As[loadK4 + 3][loadRow] = bf2f(av.w);
        Ws[loadK4 + 0][loadRow] = wv.x;
        Ws[loadK4 + 1][loadRow] = wv.y;
        Ws[loadK4 + 2][loadRow] = wv.z;
        Ws[loadK4 + 3][loadRow] = wv.w;
        __syncthreads();
        #pragma unroll
        for (int kk = 0; kk < 16; ++kk) {
            float4 a = *(const float4*)&As[kk][ty * 4];
            float4 w = *(const float4*)&Ws[kk][tx * 4];
            acc[0][0] = fmaf(a.x, w.x, acc[0][0]);
            acc[0][1] = fmaf(a.x, w.y, acc[0][1]);
            acc[0][2] = fmaf(a.x, w.z, acc[0][2]);
            acc[0][3] = fmaf(a.x, w.w, acc[0][3]);
            acc[1][0] = fmaf(a.y, w.x, acc[1][0]);
            acc[1][1] = fmaf(a.y, w.y, acc[1][1]);
            acc[1][2] = fmaf(a.y, w.z, acc[1][2]);
            acc[1][3] = fmaf(a.y, w.w, acc[1][3]);
            acc[2][0] = fmaf(a.z, w.x, acc[2][0]);
            acc[2][1] = fmaf(a.z, w.y, acc[2][1]);
            acc[2][2] = fmaf(a.z, w.z, acc[2][2]);
            acc[2][3] = fmaf(a.z, w.w, acc[2][3]);
            acc[3][0] = fmaf(a.w, w.x, acc[3][0]);
            acc[3][1] = fmaf(a.w, w.y, acc[3][1]);
            acc[3][2] = fmaf(a.w, w.z, acc[3][2]);
            acc[3][3] = fmaf(a.w, w.w, acc[3][3]);
        }
    }
    float bb[4] = {0.f, 0.f, 0.f, 0.f};
    #pragma unroll
    for (int j = 0; j < 4; ++j) {
        int col = bn + tx * 4 + j;
        if (col < N) {
            float v = 0.f;
            if (bias1) v += bias1[col];
            if (bias2) v += bias2[col];
            bb[j] = v;
        }
    }
    #pragma unroll
    for (int i = 0; i < 4; ++i) {
        int row = bm + ty * 4 + i;
        #pragma unroll
        for (int j = 0; j < 4; ++j) {
            int col = bn + tx * 4 + j;
            if (col >= N) continue;
            float v = acc[i][j] + bb[j];
            if (mode == 2) v = fast_tanh(v);
            if (mode == 0) {
                ((float*)Cout)[(size_t)col * ldc + row] = v;
            } else if (mode == 3) {
                int b = row & 31, t = row >> 5;
                ((float*)Cout)[((size_t)b * 1024 + t) * (size_t)N + col] = v;
            } else {
                ((bf16u*)Cout)[(size_t)row * N + col] = f2bf(v);
            }
        }
    }
}

// ---------------------------------------------------------------------------
// Flag barrier: each of 48 blocks stores a monotonic round to ITS OWN flag
// word (no contention); wave-0 lanes 0..47 poll all flags in parallel.
// __syncthreads() before the store drains vmcnt(0) -> prior agent-scope
// stores are at the coherence point before the flag becomes visible.
// ---------------------------------------------------------------------------
__device__ __forceinline__ void flag_barrier(uint32* flags, uint32 r,
                                             int tid, int bid) {
    __syncthreads();
    if (tid == 0)
        __hip_atomic_store(&flags[bid], r, __ATOMIC_RELAXED, __HIP_MEMORY_SCOPE_AGENT);
    if (tid < 48) {
        while (__hip_atomic_load(&flags[tid], __ATOMIC_RELAXED,
                                 __HIP_MEMORY_SCOPE_AGENT) < r) {}
    }
    __syncthreads();
}

// ---------------------------------------------------------------------------
// LSTM, one 128-step chunk. 48 blocks x 256 threads. Block owns 8 hidden
// dims (32 gate rows); Whh slice in registers as hi/lo bf16 B-frags.
// h lives in hbuf[parity][plane(hi/lo)][32 b][192 u32] -- MFMA A-frags are
// loaded DIRECTLY from global via relaxed agent-scope u64 loads (bypass
// stale L1/L2). No LDS h staging at all. Update threads (tid<128) each own
// (batch, j-pair) and pack hi/lo plane words directly.
// ---------------------------------------------------------------------------
__global__ void __launch_bounds__(256) lstm_chunk_kernel(
    const float* __restrict__ gxT,   // [1536][4096] fp32 (chunk, col=tl*32+b)
    const float* __restrict__ Whh,   // [1536][384] fp32
    const float* __restrict__ h0, const float* __restrict__ c0,
    bf16u* __restrict__ y,           // [t*32+b][384] bf16
    uint32* __restrict__ hbuf,       // [2][2][32][192] u32
    float* __restrict__ cbuf, uint32* __restrict__ flags,
    int roundBase, int t0, int is_first, int is_last,
    float* __restrict__ hs_out, float* __restrict__ cs_out)
{
    const int tid = threadIdx.x, bid = blockIdx.x;
    const int j0 = bid * 8;
    const int wave = tid >> 6, lane = tid & 63;
    const int ntile = wave & 1, mtile = wave >> 1;
    const int ncol = lane & 15, quad = lane >> 4;
    const int n = ntile * 16 + ncol;            // local gate-row 0..31
    const int wrow = (n >> 3) * 384 + j0 + (n & 7);
    const int Mrow = mtile * 16 + ncol;         // batch row for A-frag

    __shared__ float gates_s[32][33];

    // ---- B fragments: Whh rows split hi/lo bf16 (once per launch) ----
    s8v Bhi[12], Blo[12];
    #pragma unroll
    for (int kt = 0; kt < 12; ++kt) {
        const float* wp = Whh + (size_t)wrow * 384 + kt * 32 + quad * 8;
        s8v hi, lo;
        #pragma unroll
        for (int j = 0; j < 8; ++j) {
            float w = wp[j];
            bf16u wh = f2bf(w);
            bf16u wl = f2bf(w - bf2f(wh));
            hi[j] = (short)wh; lo[j] = (short)wl;
        }
        Bhi[kt] = hi; Blo[kt] = lo;
    }

    // update mapping: tid<128 owns (batch ub, j-pair jg0=j0+2*jp)
    const int ub = tid & 31, jp = tid >> 5;     // jp 0..3 valid for tid<128
    const int jg0 = j0 + 2 * jp;
    const int wcol = bid * 4 + jp;              // u32 column in planes
    float c0r = 0.f, c1r = 0.f, h0l = 0.f, h1l = 0.f;

    if (tid < 128) {
        if (is_first) {
            float ha = h0[ub * 384 + jg0], hb = h0[ub * 384 + jg0 + 1];
            bf16u ha_h = f2bf(ha); bf16u ha_l = f2bf(ha - bf2f(ha_h));
            bf16u hb_h = f2bf(hb); bf16u hb_l = f2bf(hb - bf2f(hb_h));
            // parity 0 planes
            __hip_atomic_store(&hbuf[(0 * 32 + ub) * 192 + wcol],
                               (uint32)ha_h | ((uint32)hb_h << 16),
                               __ATOMIC_RELAXED, __HIP_MEMORY_SCOPE_AGENT);
            __hip_atomic_store(&hbuf[(32 + ub) * 192 + wcol],
                               (uint32)ha_l | ((uint32)hb_l << 16),
                               __ATOMIC_RELAXED, __HIP_MEMORY_SCOPE_AGENT);
            c0r = c0[ub * 384 + jg0];
            c1r = c0[ub * 384 + jg0 + 1];
        } else {
            c0r = cbuf[ub * 384 + jg0];
            c1r = cbuf[ub * 384 + jg0 + 1];
        }
    }
    flag_barrier(flags, (uint32)(roundBase + 1), tid, bid);

    for (int tl = 0; tl < 128; ++tl) {
        const int t = t0 + tl;
        const uint32* hR = hbuf + (t & 1) * (2 * 32 * 192);
        uint32* hW = hbuf + ((t + 1) & 1) * (2 * 32 * 192);

        // gx prefetch for the update role (plain loads, L2-hot, coalesced)
        float gxv[8];
        if (tid < 128) {
            #pragma unroll
            for (int g = 0; g < 4; ++g) {
                gxv[g]     = gxT[(size_t)(g * 384 + jg0) * 4096 + tl * 32 + ub];
                gxv[4 + g] = gxT[(size_t)(g * 384 + jg0 + 1) * 4096 + tl * 32 + ub];
            }
        }

        // ---- MFMA: gates[32 b x 32 rows] = h x Whh^T (hi/lo split) ----
        const u64* hiP = (const u64*)(hR + (size_t)Mrow * 192);
        const u64* loP = (const u64*)(hR + (size_t)(32 + Mrow) * 192);
        f4v aHH = {0.f, 0.f, 0.f, 0.f};
        f4v aLH = {0.f, 0.f, 0.f, 0.f};
        f4v aHL = {0.f, 0.f, 0.f, 0.f};
        #pragma unroll
        for (int kt = 0; kt < 12; ++kt) {
            const int q0i = (kt * 16 + quad * 4) >> 1;   // u64 index
            union { u64 q[2]; s8v v; } Ah, Al;
            Ah.q[0] = __hip_atomic_load(hiP + q0i,     __ATOMIC_RELAXED, __HIP_MEMORY_SCOPE_AGENT);
            Ah.q[1] = __hip_atomic_load(hiP + q0i + 1, __ATOMIC_RELAXED, __HIP_MEMORY_SCOPE_AGENT);
            Al.q[0] = __hip_atomic_load(loP + q0i,     __ATOMIC_RELAXED, __HIP_MEMORY_SCOPE_AGENT);
            Al.q[1] = __hip_atomic_load(loP + q0i + 1, __ATOMIC_RELAXED, __HIP_MEMORY_SCOPE_AGENT);
            aHH = __builtin_amdgcn_mfma_f32_16x16x32_bf16(Ah.v, Bhi[kt], aHH, 0, 0, 0);
            aLH = __builtin_amdgcn_mfma_f32_16x16x32_bf16(Al.v, Bhi[kt], aLH, 0, 0, 0);
            aHL = __builtin_amdgcn_mfma_f32_16x16x32_bf16(Ah.v, Blo[kt], aHL, 0, 0, 0);
        }
        #pragma unroll
        for (int r = 0; r < 4; ++r)
            gates_s[n][mtile * 16 + quad * 4 + r] = aHH[r] + aLH[r] + aHL[r];
        __syncthreads();

        // ---- cell update: tid<128, two hidden dims each ----
        if (tid < 128) {
            const int jj0 = 2 * jp, jj1 = 2 * jp + 1;
            float pi0 = gates_s[jj0][ub]      + gxv[0];
            float pf0 = gates_s[8 + jj0][ub]  + gxv[1];
            float pg0 = gates_s[16 + jj0][ub] + gxv[2];
            float po0 = gates_s[24 + jj0][ub] + gxv[3];
            float pi1 = gates_s[jj1][ub]      + gxv[4];
            float pf1 = gates_s[8 + jj1][ub]  + gxv[5];
            float pg1 = gates_s[16 + jj1][ub] + gxv[6];
            float po1 = gates_s[24 + jj1][ub] + gxv[7];
            c0r = sigmoidf(pf0) * c0r + sigmoidf(pi0) * fast_tanh(pg0);
            c1r = sigmoidf(pf1) * c1r + sigmoidf(pi1) * fast_tanh(pg1);
            float hv0 = sigmoidf(po0) * fast_tanh(c0r);
            float hv1 = sigmoidf(po1) * fast_tanh(c1r);
            h0l = hv0; h1l = hv1;
            bf16u h0h = f2bf(hv0); bf16u h0lo = f2bf(hv0 - bf2f(h0h));
            bf16u h1h = f2bf(hv1); bf16u h1lo = f2bf(hv1 - bf2f(h1h));
            __hip_atomic_store(&hW[(0 * 32 + ub) * 192 + wcol],
                               (uint32)h0h | ((uint32)h1h << 16),
                               __ATOMIC_RELAXED, __HIP_MEMORY_SCOPE_AGENT);
            __hip_atomic_store(&hW[(32 + ub) * 192 + wcol],
                               (uint32)h0lo | ((uint32)h1lo << 16),
                               __ATOMIC_RELAXED, __HIP_MEMORY_SCOPE_AGENT);
            // y output (plain store; consumed by later dispatches only)
            *(uint32*)(y + ((size_t)t * 32 + ub) * 384 + jg0) =
                (uint32)h0h | ((uint32)h1h << 16);
        }
        flag_barrier(flags, (uint32)(roundBase + tl + 2), tid, bid);
    }

    if (tid < 128) {
        cbuf[ub * 384 + jg0]     = c0r;
        cbuf[ub * 384 + jg0 + 1] = c1r;
        if (is_last) {
            hs_out[ub * 384 + jg0]     = h0l;
            hs_out[ub * 384 + jg0 + 1] = h1l;
            cs_out[ub * 384 + jg0]     = c0r;
            cs_out[ub * 384 + jg0 + 1] = c1r;
        }
    }
}

// ---------------------------------------------------------------------------
// Causal flash attention, bf16 in/out (unchanged from passing round).
// ---------------------------------------------------------------------------
__global__ void __launch_bounds__(256) attn_kernel(
    const bf16u* __restrict__ outy, const bf16u* __restrict__ keys,
    bf16u* __restrict__ ctxv)
{
    const int b = blockIdx.y;
    const int q0 = blockIdx.x * 32;
    const int tid = threadIdx.x;
    __shared__ uint32 Qs[32][194];
    __shared__ uint32 Ks[16][194];
    __shared__ uint32 Vs[16][192];
    __shared__ float Ss[32][16];
    __shared__ float m_s[32], l_s[32], alpha_s[32];

    for (int i = tid; i < 32 * 192; i += 256) {
        int q = i / 192, dp = i - q * 192;
        Qs[q][dp] = ((const uint32*)(outy + ((size_t)(q0 + q) * 32 + b) * 384))[dp];
    }
    if (tid < 32) { m_s[tid] = -3e38f; l_s[tid] = 0.f; }

    const int qo = tid >> 3, dg = tid & 7;
    float O[48];
    #pragma unroll
    for (int d = 0; d < 48; ++d) O[d] = 0.f;

    const int nkt = (q0 + 32) >> 4;
    for (int kt = 0; kt < nkt; ++kt) {
        const int k0 = kt * 16;
        __syncthreads();
        for (int i = tid; i < 16 * 192; i += 256) {
            int kk = i / 192, dp = i - kk * 192;
            size_t rt = (size_t)(k0 + kk) * 32 + b;
            Ks[kk][dp] = ((const uint32*)(keys + rt * 384))[dp];
            Vs[kk][dp] = ((const uint32*)(outy + rt * 384))[dp];
        }
        __syncthreads();
        #pragma unroll
        for (int pp = 0; pp < 2; ++pp) {
            int p = tid + pp * 256;
            int q = p >> 4, k = p & 15;
            const uint32* qrow = Qs[q];
            const uint32* krow = Ks[k];
            float acc = 0.f;
            for (int dp = 0; dp < 192; ++dp) {
                uint32 qa = qrow[dp], ka = krow[dp];
                acc = fmaf(bflo(qa), bflo(ka), acc);
                acc = fmaf(bfhi(qa), bfhi(ka), acc);
            }
            acc *= 0.051031036307982884f;    // 1/sqrt(384)
            Ss[q][k] = ((k0 + k) <= (q0 + q)) ? acc : -1e30f;
        }
        __syncthreads();
        if (tid < 32) {
            int q = tid;
            float mt = m_s[q];
            #pragma unroll
            for (int k = 0; k < 16; ++k) mt = fmaxf(mt, Ss[q][k]);
            float alpha = __expf(m_s[q] - mt);
            float l = l_s[q] * alpha;
            #pragma unroll
            for (int k = 0; k < 16; ++k) {
                float pv = __expf(Ss[q][k] - mt);
                Ss[q][k] = pv;
                l += pv;
            }
            m_s[q] = mt; l_s[q] = l; alpha_s[q] = alpha;
        }
        __syncthreads();
        {
            float al = alpha_s[qo];
            #pragma unroll
            for (int d = 0; d < 48; ++d) O[d] *= al;
            for (int k = 0; k < 16; ++k) {
                float pv = Ss[qo][k];
                const uint32* vrow = Vs[k] + dg * 24;
                #pragma unroll
                for (int dp = 0; dp < 24; ++dp) {
                    uint32 va = vrow[dp];
                    O[2 * dp]     = fmaf(pv, bflo(va), O[2 * dp]);
                    O[2 * dp + 1] = fmaf(pv, bfhi(va), O[2 * dp + 1]);
                }
            }
        }
    }
    float inv = 1.f / l_s[qo];
    uint32* dst = (uint32*)(ctxv + ((size_t)(q0 + qo) * 32 + b) * 384) + dg * 24;
    #pragma unroll
    for (int dp = 0; dp < 24; ++dp)
        dst[dp] = pack2bf(O[2 * dp] * inv, O[2 * dp + 1] * inv);
}

// ---------------------------------------------------------------------------
extern "C" void kernel_launch(void* const* d_in, const int* in_sizes, int n_in,
                              void* d_out, int out_size, void* d_ws, size_t ws_size,
                              hipStream_t stream) {
    (void)in_sizes; (void)n_in; (void)out_size; (void)ws_size;
    const int*   x        = (const int*)d_in[0];
    const float* context  = (const float*)d_in[1];
    const float* h_in     = (const float*)d_in[2];
    const float* c_in     = (const float*)d_in[3];
    const float* emb      = (const float*)d_in[4];
    const float* ctx_W    = (const float*)d_in[5];
    const float* ctx_b    = (const float*)d_in[6];
    const float* Wih0     = (const float*)d_in[7];
    const float* Wih_rest = (const float*)d_in[8];
    const float* Whh      = (const float*)d_in[9];
    const float* bih      = (const float*)d_in[10];
    const float* bhh      = (const float*)d_in[11];
    const float* Wa       = (const float*)d_in[12];
    const float* comb_W   = (const float*)d_in[13];
    const float* comb_b   = (const float*)d_in[14];
    const float* fc_W     = (const float*)d_in[15];
    const float* fc_b     = (const float*)d_in[16];
    float* out = (float*)d_out;

    // ---- workspace layout (identical footprint to the passing round) ----
    char* wsb = (char*)d_ws;
    uint32* flags = (uint32*)(wsb + 0);               //   1 KB (48 flags used)
    uint32* hbuf  = (uint32*)(wsb + 1024);            //  96 KB [2][2][32][192]
    float*  cbuf  = (float*)(wsb + 99328);            //  48 KB [32][384]
    bf16u*  inp   = (bf16u*)(wsb + 148480);           //  16.78 MB [32768,256]
    bf16u*  yA    = (bf16u*)(wsb + 16925696ull);      //  25.17 MB [32768,384]
    bf16u*  yB    = (bf16u*)(wsb + 42091520ull);      //  25.17 MB [32768,384]
    float*  gxT   = (float*)(wsb + 67257344ull);      //  25.17 MB [1536,4096]
    bf16u* keysu = (bf16u*)gxT;                       // reuse after LSTM stack
    bf16u* ctxvu = yA;                                // reuse (layer-2 y dead)
    bf16u* combu = (bf16u*)gxT;                       // reuse after attention

    hipMemsetAsync(d_ws, 0, 1024, stream);            // zero flags

    embed_ctx_kernel<<<2048, 128, 0, stream>>>(x, context, emb, ctx_W, ctx_b, inp);

    const size_t HS_OFF = (size_t)32768 * 100;
    for (int l = 0; l < 4; ++l) {
        const int K = l ? 384 : 256;
        const float* Wl = l ? (Wih_rest + (size_t)(l - 1) * 1536 * 384) : Wih0;
        const bf16u* Ain = (l == 0) ? inp : ((l == 1 || l == 3) ? yA : yB);
        bf16u* yl = (l & 1) ? yB : yA;
        for (int c = 0; c < 8; ++c) {
            gemm_kernel<<<dim3(24, 64), 256, 0, stream>>>(
                Ain + (size_t)c * 4096 * K, nullptr, K, Wl,
                bih + l * 1536, bhh + l * 1536, gxT, 4096, 1536, K, 0, 4096);
            lstm_chunk_kernel<<<48, 256, 0, stream>>>(
                gxT, Whh + (size_t)l * 1536 * 384,
                h_in + l * 12288, c_in + l * 12288,
                yl, hbuf, cbuf, flags,
                (l * 8 + c) * 130, c * 128,
                c == 0, c == 7,
                out + HS_OFF + l * 12288, out + HS_OFF + 49152 + l * 12288);
        }
    }
    // keys = y3 @ Wa^T  (yB -> gxT region, bf16)
    gemm_kernel<<<dim3(6, 512), 256, 0, stream>>>(
        yB, nullptr, 384, Wa, nullptr, nullptr, keysu, 32768, 384, 384, 1, 0);
    // ctx_vec (flash attention)  (yB, keys -> yA region)
    attn_kernel<<<dim3(32, 32), 256, 0, stream>>>(yB, keysu, ctxvu);
    // combined = tanh([y3, ctx] @ comb_W^T + b)  (-> gxT region, bf16)
    gemm_kernel<<<dim3(6, 512), 256, 0, stream>>>(
        yB, ctxvu, 384, comb_W, comb_b, nullptr, combu, 32768, 384, 768, 2, 0);
    // logits = combined @ fc_W^T + fc_b  (-> d_out, permuted to [b][t][100])
    gemm_kernel<<<dim3(2, 512), 256, 0, stream>>>(
        combu, nullptr, 384, fc_W, fc_b, nullptr, out, 32768, 100, 384, 3, 0);
}

// Round 5
// 37347.079 us; speedup vs baseline: 2.9150x; 1.0428x over previous
//
#include <hip/hip_runtime.h>

typedef unsigned int  uint32;
typedef unsigned long long u64;
typedef unsigned short bf16u;
typedef __attribute__((ext_vector_type(8))) short s8v;    // 8 bf16 (4 VGPRs)
typedef __attribute__((ext_vector_type(4))) float f4v;    // MFMA acc

__device__ __forceinline__ float fast_tanh(float x) {
    x = fminf(9.f, fmaxf(-9.f, x));
    float e = __expf(2.f * x);
    return (e - 1.f) / (e + 1.f);
}
__device__ __forceinline__ float sigmoidf(float x) {
    return 1.f / (1.f + __expf(-x));
}
__device__ __forceinline__ bf16u f2bf(float f) {
    uint32 u = __float_as_uint(f);
    u += 0x7fffu + ((u >> 16) & 1u);
    return (bf16u)(u >> 16);
}
__device__ __forceinline__ float bf2f(bf16u u) {
    return __uint_as_float(((uint32)u) << 16);
}
__device__ __forceinline__ uint32 pack2bf(float lo, float hi) {
    return (uint32)f2bf(lo) | ((uint32)f2bf(hi) << 16);
}
__device__ __forceinline__ float bflo(uint32 p) { return __uint_as_float(p << 16); }
__device__ __forceinline__ float bfhi(uint32 p) { return __uint_as_float(p & 0xffff0000u); }

// ---------------------------------------------------------------------------
// Embedding + context projection -> inp [rt=t*32+b][256] bf16 (emb || ctx)
// ---------------------------------------------------------------------------
__global__ void __launch_bounds__(128) embed_ctx_kernel(
    const int* __restrict__ x, const float* __restrict__ ctx,
    const float* __restrict__ emb, const float* __restrict__ ctxW,
    const float* __restrict__ ctxb, bf16u* __restrict__ inp)
{
    const int r0 = blockIdx.x * 16;
    const int tid = threadIdx.x;
    __shared__ float cs[16][301];
    __shared__ int xs[16];
    for (int i = tid; i < 16 * 300; i += 128) {
        int row = i / 300, k = i - row * 300;
        int rt = r0 + row, b = rt & 31, t = rt >> 5;
        cs[row][k] = ctx[((size_t)b * 1024 + t) * 300 + k];
    }
    if (tid < 16) {
        int rt = r0 + tid;
        xs[tid] = x[(rt & 31) * 1024 + (rt >> 5)];
    }
    __syncthreads();
    float acc[16];
    #pragma unroll
    for (int row = 0; row < 16; ++row) acc[row] = 0.f;
    for (int k = 0; k < 300; ++k) {
        float w = ctxW[tid * 300 + k];
        #pragma unroll
        for (int row = 0; row < 16; ++row) acc[row] = fmaf(w, cs[row][k], acc[row]);
    }
    float bb = ctxb[tid];
    for (int row = 0; row < 16; ++row) {
        size_t base = (size_t)(r0 + row) * 256;
        inp[base + tid]       = f2bf(emb[xs[row] * 128 + tid]);
        inp[base + 128 + tid] = f2bf(acc[row] + bb);
    }
}

// ---------------------------------------------------------------------------
// MFMA GEMM: C[M,N] = A[M,K](bf16) @ W[N,K]^T(f32, split hi/lo bf16)
// A split at K0 between A0/A1 (both bf16, row strides K0 / K-K0).
// mode 0: f32 out TRANSPOSED -> Cout[col*ldc + row]  (for gxT)
// mode 1: bf16 out; mode 2: bf16+tanh; mode 3: f32 out, row rt->(b*1024+t).
// BM=BN=64, BK=32; 4 waves, each a 32x32 quadrant via 2x2 16x16x32 MFMAs.
// M, K multiples of 64/32; N may be ragged (masked).
// ---------------------------------------------------------------------------
__global__ void __launch_bounds__(256) gemm_kernel(
    const bf16u* __restrict__ A0, const bf16u* __restrict__ A1, int K0,
    const float* __restrict__ W, const float* __restrict__ bias1,
    const float* __restrict__ bias2, void* __restrict__ Cout,
    int M, int N, int K, int mode, int ldc)
{
    __shared__ bf16u As[64][40];     // row stride 40 bf16 = 80 B (2-way max)
    __shared__ bf16u Whi[64][40];
    __shared__ bf16u Wlo[64][40];
    const int tid = threadIdx.x;
    const int bn = blockIdx.x * 64, bm = blockIdx.y * 64;
    const int wave = tid >> 6, lane = tid & 63;
    const int wm = wave >> 1, wn = wave & 1;
    const int ncol = lane & 15, quad = lane >> 4;
    const int lr = tid >> 2, lk = (tid & 3) * 8;   // loader: row, k-offset

    f4v acc[2][2];
    #pragma unroll
    for (int i = 0; i < 2; ++i)
        #pragma unroll
        for (int j = 0; j < 2; ++j) acc[i][j] = (f4v){0.f, 0.f, 0.f, 0.f};

    const int wrow = bn + lr;
    for (int k0 = 0; k0 < K; k0 += 32) {
        const bf16u* Ab; int kb, lda;
        if (k0 < K0) { Ab = A0; kb = k0; lda = K0; }
        else         { Ab = A1; kb = k0 - K0; lda = K - K0; }
        uint4 av = *(const uint4*)(Ab + (size_t)(bm + lr) * lda + kb + lk);
        float4 w0 = make_float4(0.f, 0.f, 0.f, 0.f), w1 = w0;
        if (wrow < N) {
            const float* wp = W + (size_t)wrow * K + k0 + lk;
            w0 = *(const float4*)wp;
            w1 = *(const float4*)(wp + 4);
        }
        __syncthreads();
        *(uint4*)&As[lr][lk] = av;
        {
            bf16u h[8], l[8];
            float wf[8] = {w0.x, w0.y, w0.z, w0.w, w1.x, w1.y, w1.z, w1.w};
            #pragma unroll
            for (int j = 0; j < 8; ++j) {
                h[j] = f2bf(wf[j]);
                l[j] = f2bf(wf[j] - bf2f(h[j]));
            }
            #pragma unroll
            for (int j = 0; j < 8; ++j) Whi[lr][lk + j] = h[j];
            #pragma unroll
            for (int j = 0; j < 8; ++j) Wlo[lr][lk + j] = l[j];
        }
        __syncthreads();
        s8v aF[2], bH[2], bL[2];
        #pragma unroll
        for (int mt = 0; mt < 2; ++mt)
            aF[mt] = *(const s8v*)&As[wm * 32 + mt * 16 + ncol][quad * 8];
        #pragma unroll
        for (int nt = 0; nt < 2; ++nt) {
            bH[nt] = *(const s8v*)&Whi[wn * 32 + nt * 16 + ncol][quad * 8];
            bL[nt] = *(const s8v*)&Wlo[wn * 32 + nt * 16 + ncol][quad * 8];
        }
        #pragma unroll
        for (int mt = 0; mt < 2; ++mt)
            #pragma unroll
            for (int nt = 0; nt < 2; ++nt) {
                acc[mt][nt] = __builtin_amdgcn_mfma_f32_16x16x32_bf16(
                    aF[mt], bH[nt], acc[mt][nt], 0, 0, 0);
                acc[mt][nt] = __builtin_amdgcn_mfma_f32_16x16x32_bf16(
                    aF[mt], bL[nt], acc[mt][nt], 0, 0, 0);
            }
    }

    // epilogue: C row = bm+wm*32+mt*16+quad*4+reg, col = bn+wn*32+nt*16+ncol
    #pragma unroll
    for (int nt = 0; nt < 2; ++nt) {
        const int col = bn + wn * 32 + nt * 16 + ncol;
        if (col >= N) continue;
        float bb = 0.f;
        if (bias1) bb += bias1[col];
        if (bias2) bb += bias2[col];
        #pragma unroll
        for (int mt = 0; mt < 2; ++mt) {
            const int rowb = bm + wm * 32 + mt * 16 + quad * 4;
            if (mode == 0) {
                float4 v;
                v.x = acc[mt][nt][0] + bb;
                v.y = acc[mt][nt][1] + bb;
                v.z = acc[mt][nt][2] + bb;
                v.w = acc[mt][nt][3] + bb;
                *(float4*)((float*)Cout + (size_t)col * ldc + rowb) = v;
            } else if (mode == 3) {
                #pragma unroll
                for (int r = 0; r < 4; ++r) {
                    int row = rowb + r;
                    int b = row & 31, t = row >> 5;
                    ((float*)Cout)[((size_t)b * 1024 + t) * (size_t)N + col] =
                        acc[mt][nt][r] + bb;
                }
            } else {
                #pragma unroll
                for (int r = 0; r < 4; ++r) {
                    float v = acc[mt][nt][r] + bb;
                    if (mode == 2) v = fast_tanh(v);
                    ((bf16u*)Cout)[(size_t)(rowb + r) * N + col] = f2bf(v);
                }
            }
        }
    }
}

// ---------------------------------------------------------------------------
// Flag barrier: each of 48 blocks stores a monotonic round to ITS OWN flag
// word; wave-0 lanes 0..47 poll all flags in parallel with s_sleep backoff.
// __syncthreads() before the store drains vmcnt(0) -> prior agent-scope
// stores are at the coherence point before the flag becomes visible.
// ---------------------------------------------------------------------------
__device__ __forceinline__ void flag_barrier(uint32* flags, uint32 r,
                                             int tid, int bid) {
    __syncthreads();
    if (tid == 0)
        __hip_atomic_store(&flags[bid], r, __ATOMIC_RELAXED, __HIP_MEMORY_SCOPE_AGENT);
    if (tid < 48) {
        while (__hip_atomic_load(&flags[tid], __ATOMIC_RELAXED,
                                 __HIP_MEMORY_SCOPE_AGENT) < r)
            __builtin_amdgcn_s_sleep(1);
    }
    __syncthreads();
}

// ---------------------------------------------------------------------------
// LSTM, one 128-step chunk. 48 blocks x 256 threads. Block owns 8 hidden
// dims (32 gate rows); Whh slice in registers as hi/lo bf16 B-frags.
// h lives in hbuf[parity][plane(hi/lo)][32 b][192 u32] -- MFMA A-frags are
// loaded DIRECTLY from global via relaxed agent-scope u64 loads (bypass
// stale L1/L2). No LDS h staging. Update threads (tid<128) each own
// (batch, j-pair) and pack hi/lo plane words directly.
// ---------------------------------------------------------------------------
__global__ void __launch_bounds__(256) lstm_chunk_kernel(
    const float* __restrict__ gxT,   // [1536][4096] fp32 (chunk, col=tl*32+b)
    const float* __restrict__ Whh,   // [1536][384] fp32
    const float* __restrict__ h0, const float* __restrict__ c0,
    bf16u* __restrict__ y,           // [t*32+b][384] bf16
    uint32* __restrict__ hbuf,       // [2][2][32][192] u32
    float* __restrict__ cbuf, uint32* __restrict__ flags,
    int roundBase, int t0, int is_first, int is_last,
    float* __restrict__ hs_out, float* __restrict__ cs_out)
{
    const int tid = threadIdx.x, bid = blockIdx.x;
    const int j0 = bid * 8;
    const int wave = tid >> 6, lane = tid & 63;
    const int ntile = wave & 1, mtile = wave >> 1;
    const int ncol = lane & 15, quad = lane >> 4;
    const int n = ntile * 16 + ncol;            // local gate-row 0..31
    const int wrow = (n >> 3) * 384 + j0 + (n & 7);
    const int Mrow = mtile * 16 + ncol;         // batch row for A-frag

    __shared__ float gates_s[32][33];

    // ---- B fragments: Whh rows split hi/lo bf16 (once per launch) ----
    s8v Bhi[12], Blo[12];
    #pragma unroll
    for (int kt = 0; kt < 12; ++kt) {
        const float* wp = Whh + (size_t)wrow * 384 + kt * 32 + quad * 8;
        s8v hi, lo;
        #pragma unroll
        for (int j = 0; j < 8; ++j) {
            float w = wp[j];
            bf16u wh = f2bf(w);
            bf16u wl = f2bf(w - bf2f(wh));
            hi[j] = (short)wh; lo[j] = (short)wl;
        }
        Bhi[kt] = hi; Blo[kt] = lo;
    }

    // update mapping: tid<128 owns (batch ub, j-pair jg0=j0+2*jp)
    const int ub = tid & 31, jp = tid >> 5;     // jp 0..3 valid for tid<128
    const int jg0 = j0 + 2 * jp;
    const int wcol = bid * 4 + jp;              // u32 column in planes
    float c0r = 0.f, c1r = 0.f, h0l = 0.f, h1l = 0.f;

    if (tid < 128) {
        if (is_first) {
            float ha = h0[ub * 384 + jg0], hb = h0[ub * 384 + jg0 + 1];
            bf16u ha_h = f2bf(ha); bf16u ha_l = f2bf(ha - bf2f(ha_h));
            bf16u hb_h = f2bf(hb); bf16u hb_l = f2bf(hb - bf2f(hb_h));
            __hip_atomic_store(&hbuf[(0 * 32 + ub) * 192 + wcol],
                               (uint32)ha_h | ((uint32)hb_h << 16),
                               __ATOMIC_RELAXED, __HIP_MEMORY_SCOPE_AGENT);
            __hip_atomic_store(&hbuf[(32 + ub) * 192 + wcol],
                               (uint32)ha_l | ((uint32)hb_l << 16),
                               __ATOMIC_RELAXED, __HIP_MEMORY_SCOPE_AGENT);
            c0r = c0[ub * 384 + jg0];
            c1r = c0[ub * 384 + jg0 + 1];
        } else {
            c0r = cbuf[ub * 384 + jg0];
            c1r = cbuf[ub * 384 + jg0 + 1];
        }
    }
    flag_barrier(flags, (uint32)(roundBase + 1), tid, bid);

    for (int tl = 0; tl < 128; ++tl) {
        const int t = t0 + tl;
        const uint32* hR = hbuf + (t & 1) * (2 * 32 * 192);
        uint32* hW = hbuf + ((t + 1) & 1) * (2 * 32 * 192);

        // gx prefetch for the update role (plain loads, L2-hot, coalesced)
        float gxv[8];
        if (tid < 128) {
            #pragma unroll
            for (int g = 0; g < 4; ++g) {
                gxv[g]     = gxT[(size_t)(g * 384 + jg0) * 4096 + tl * 32 + ub];
                gxv[4 + g] = gxT[(size_t)(g * 384 + jg0 + 1) * 4096 + tl * 32 + ub];
            }
        }

        // ---- MFMA: gates[32 b x 32 rows] = h x Whh^T (hi/lo split) ----
        const u64* hiP = (const u64*)(hR + (size_t)Mrow * 192);
        const u64* loP = (const u64*)(hR + (size_t)(32 + Mrow) * 192);
        f4v aHH = {0.f, 0.f, 0.f, 0.f};
        f4v aLH = {0.f, 0.f, 0.f, 0.f};
        f4v aHL = {0.f, 0.f, 0.f, 0.f};
        #pragma unroll
        for (int kt = 0; kt < 12; ++kt) {
            const int q0i = (kt * 16 + quad * 4) >> 1;   // u64 index
            union { u64 q[2]; s8v v; } Ah, Al;
            Ah.q[0] = __hip_atomic_load(hiP + q0i,     __ATOMIC_RELAXED, __HIP_MEMORY_SCOPE_AGENT);
            Ah.q[1] = __hip_atomic_load(hiP + q0i + 1, __ATOMIC_RELAXED, __HIP_MEMORY_SCOPE_AGENT);
            Al.q[0] = __hip_atomic_load(loP + q0i,     __ATOMIC_RELAXED, __HIP_MEMORY_SCOPE_AGENT);
            Al.q[1] = __hip_atomic_load(loP + q0i + 1, __ATOMIC_RELAXED, __HIP_MEMORY_SCOPE_AGENT);
            aHH = __builtin_amdgcn_mfma_f32_16x16x32_bf16(Ah.v, Bhi[kt], aHH, 0, 0, 0);
            aLH = __builtin_amdgcn_mfma_f32_16x16x32_bf16(Al.v, Bhi[kt], aLH, 0, 0, 0);
            aHL = __builtin_amdgcn_mfma_f32_16x16x32_bf16(Ah.v, Blo[kt], aHL, 0, 0, 0);
        }
        #pragma unroll
        for (int r = 0; r < 4; ++r)
            gates_s[n][mtile * 16 + quad * 4 + r] = aHH[r] + aLH[r] + aHL[r];
        __syncthreads();

        // ---- cell update: tid<128, two hidden dims each ----
        if (tid < 128) {
            const int jj0 = 2 * jp, jj1 = 2 * jp + 1;
            float pi0 = gates_s[jj0][ub]      + gxv[0];
            float pf0 = gates_s[8 + jj0][ub]  + gxv[1];
            float pg0 = gates_s[16 + jj0][ub] + gxv[2];
            float po0 = gates_s[24 + jj0][ub] + gxv[3];
            float pi1 = gates_s[jj1][ub]      + gxv[4];
            float pf1 = gates_s[8 + jj1][ub]  + gxv[5];
            float pg1 = gates_s[16 + jj1][ub] + gxv[6];
            float po1 = gates_s[24 + jj1][ub] + gxv[7];
            c0r = sigmoidf(pf0) * c0r + sigmoidf(pi0) * fast_tanh(pg0);
            c1r = sigmoidf(pf1) * c1r + sigmoidf(pi1) * fast_tanh(pg1);
            float hv0 = sigmoidf(po0) * fast_tanh(c0r);
            float hv1 = sigmoidf(po1) * fast_tanh(c1r);
            h0l = hv0; h1l = hv1;
            bf16u h0h = f2bf(hv0); bf16u h0lo = f2bf(hv0 - bf2f(h0h));
            bf16u h1h = f2bf(hv1); bf16u h1lo = f2bf(hv1 - bf2f(h1h));
            __hip_atomic_store(&hW[(0 * 32 + ub) * 192 + wcol],
                               (uint32)h0h | ((uint32)h1h << 16),
                               __ATOMIC_RELAXED, __HIP_MEMORY_SCOPE_AGENT);
            __hip_atomic_store(&hW[(32 + ub) * 192 + wcol],
                               (uint32)h0lo | ((uint32)h1lo << 16),
                               __ATOMIC_RELAXED, __HIP_MEMORY_SCOPE_AGENT);
            *(uint32*)(y + ((size_t)t * 32 + ub) * 384 + jg0) =
                (uint32)h0h | ((uint32)h1h << 16);
        }
        flag_barrier(flags, (uint32)(roundBase + tl + 2), tid, bid);
    }

    if (tid < 128) {
        cbuf[ub * 384 + jg0]     = c0r;
        cbuf[ub * 384 + jg0 + 1] = c1r;
        if (is_last) {
            hs_out[ub * 384 + jg0]     = h0l;
            hs_out[ub * 384 + jg0 + 1] = h1l;
            cs_out[ub * 384 + jg0]     = c0r;
            cs_out[ub * 384 + jg0 + 1] = c1r;
        }
    }
}

// ---------------------------------------------------------------------------
// Causal flash attention, bf16 in/out (unchanged from passing round).
// ---------------------------------------------------------------------------
__global__ void __launch_bounds__(256) attn_kernel(
    const bf16u* __restrict__ outy, const bf16u* __restrict__ keys,
    bf16u* __restrict__ ctxv)
{
    const int b = blockIdx.y;
    const int q0 = blockIdx.x * 32;
    const int tid = threadIdx.x;
    __shared__ uint32 Qs[32][194];
    __shared__ uint32 Ks[16][194];
    __shared__ uint32 Vs[16][192];
    __shared__ float Ss[32][16];
    __shared__ float m_s[32], l_s[32], alpha_s[32];

    for (int i = tid; i < 32 * 192; i += 256) {
        int q = i / 192, dp = i - q * 192;
        Qs[q][dp] = ((const uint32*)(outy + ((size_t)(q0 + q) * 32 + b) * 384))[dp];
    }
    if (tid < 32) { m_s[tid] = -3e38f; l_s[tid] = 0.f; }

    const int qo = tid >> 3, dg = tid & 7;
    float O[48];
    #pragma unroll
    for (int d = 0; d < 48; ++d) O[d] = 0.f;

    const int nkt = (q0 + 32) >> 4;
    for (int kt = 0; kt < nkt; ++kt) {
        const int k0 = kt * 16;
        __syncthreads();
        for (int i = tid; i < 16 * 192; i += 256) {
            int kk = i / 192, dp = i - kk * 192;
            size_t rt = (size_t)(k0 + kk) * 32 + b;
            Ks[kk][dp] = ((const uint32*)(keys + rt * 384))[dp];
            Vs[kk][dp] = ((const uint32*)(outy + rt * 384))[dp];
        }
        __syncthreads();
        #pragma unroll
        for (int pp = 0; pp < 2; ++pp) {
            int p = tid + pp * 256;
            int q = p >> 4, k = p & 15;
            const uint32* qrow = Qs[q];
            const uint32* krow = Ks[k];
            float acc = 0.f;
            for (int dp = 0; dp < 192; ++dp) {
                uint32 qa = qrow[dp], ka = krow[dp];
                acc = fmaf(bflo(qa), bflo(ka), acc);
                acc = fmaf(bfhi(qa), bfhi(ka), acc);
            }
            acc *= 0.051031036307982884f;    // 1/sqrt(384)
            Ss[q][k] = ((k0 + k) <= (q0 + q)) ? acc : -1e30f;
        }
        __syncthreads();
        if (tid < 32) {
            int q = tid;
            float mt = m_s[q];
            #pragma unroll
            for (int k = 0; k < 16; ++k) mt = fmaxf(mt, Ss[q][k]);
            float alpha = __expf(m_s[q] - mt);
            float l = l_s[q] * alpha;
            #pragma unroll
            for (int k = 0; k < 16; ++k) {
                float pv = __expf(Ss[q][k] - mt);
                Ss[q][k] = pv;
                l += pv;
            }
            m_s[q] = mt; l_s[q] = l; alpha_s[q] = alpha;
        }
        __syncthreads();
        {
            float al = alpha_s[qo];
            #pragma unroll
            for (int d = 0; d < 48; ++d) O[d] *= al;
            for (int k = 0; k < 16; ++k) {
                float pv = Ss[qo][k];
                const uint32* vrow = Vs[k] + dg * 24;
                #pragma unroll
                for (int dp = 0; dp < 24; ++dp) {
                    uint32 va = vrow[dp];
                    O[2 * dp]     = fmaf(pv, bflo(va), O[2 * dp]);
                    O[2 * dp + 1] = fmaf(pv, bfhi(va), O[2 * dp + 1]);
                }
            }
        }
    }
    float inv = 1.f / l_s[qo];
    uint32* dst = (uint32*)(ctxv + ((size_t)(q0 + qo) * 32 + b) * 384) + dg * 24;
    #pragma unroll
    for (int dp = 0; dp < 24; ++dp)
        dst[dp] = pack2bf(O[2 * dp] * inv, O[2 * dp + 1] * inv);
}

// ---------------------------------------------------------------------------
extern "C" void kernel_launch(void* const* d_in, const int* in_sizes, int n_in,
                              void* d_out, int out_size, void* d_ws, size_t ws_size,
                              hipStream_t stream) {
    (void)in_sizes; (void)n_in; (void)out_size; (void)ws_size;
    const int*   x        = (const int*)d_in[0];
    const float* context  = (const float*)d_in[1];
    const float* h_in     = (const float*)d_in[2];
    const float* c_in     = (const float*)d_in[3];
    const float* emb      = (const float*)d_in[4];
    const float* ctx_W    = (const float*)d_in[5];
    const float* ctx_b    = (const float*)d_in[6];
    const float* Wih0     = (const float*)d_in[7];
    const float* Wih_rest = (const float*)d_in[8];
    const float* Whh      = (const float*)d_in[9];
    const float* bih      = (const float*)d_in[10];
    const float* bhh      = (const float*)d_in[11];
    const float* Wa       = (const float*)d_in[12];
    const float* comb_W   = (const float*)d_in[13];
    const float* comb_b   = (const float*)d_in[14];
    const float* fc_W     = (const float*)d_in[15];
    const float* fc_b     = (const float*)d_in[16];
    float* out = (float*)d_out;

    // ---- workspace layout (identical footprint to the passing round) ----
    char* wsb = (char*)d_ws;
    uint32* flags = (uint32*)(wsb + 0);               //   1 KB (48 flags used)
    uint32* hbuf  = (uint32*)(wsb + 1024);            //  96 KB [2][2][32][192]
    float*  cbuf  = (float*)(wsb + 99328);            //  48 KB [32][384]
    bf16u*  inp   = (bf16u*)(wsb + 148480);           //  16.78 MB [32768,256]
    bf16u*  yA    = (bf16u*)(wsb + 16925696ull);      //  25.17 MB [32768,384]
    bf16u*  yB    = (bf16u*)(wsb + 42091520ull);      //  25.17 MB [32768,384]
    float*  gxT   = (float*)(wsb + 67257344ull);      //  25.17 MB [1536,4096]
    bf16u* keysu = (bf16u*)gxT;                       // reuse after LSTM stack
    bf16u* ctxvu = yA;                                // reuse (layer-2 y dead)
    bf16u* combu = (bf16u*)gxT;                       // reuse after attention

    hipMemsetAsync(d_ws, 0, 1024, stream);            // zero flags

    embed_ctx_kernel<<<2048, 128, 0, stream>>>(x, context, emb, ctx_W, ctx_b, inp);

    const size_t HS_OFF = (size_t)32768 * 100;
    for (int l = 0; l < 4; ++l) {
        const int K = l ? 384 : 256;
        const float* Wl = l ? (Wih_rest + (size_t)(l - 1) * 1536 * 384) : Wih0;
        const bf16u* Ain = (l == 0) ? inp : ((l == 1 || l == 3) ? yA : yB);
        bf16u* yl = (l & 1) ? yB : yA;
        for (int c = 0; c < 8; ++c) {
            gemm_kernel<<<dim3(24, 64), 256, 0, stream>>>(
                Ain + (size_t)c * 4096 * K, nullptr, K, Wl,
                bih + l * 1536, bhh + l * 1536, gxT, 4096, 1536, K, 0, 4096);
            lstm_chunk_kernel<<<48, 256, 0, stream>>>(
                gxT, Whh + (size_t)l * 1536 * 384,
                h_in + l * 12288, c_in + l * 12288,
                yl, hbuf, cbuf, flags,
                (l * 8 + c) * 130, c * 128,
                c == 0, c == 7,
                out + HS_OFF + l * 12288, out + HS_OFF + 49152 + l * 12288);
        }
    }
    // keys = y3 @ Wa^T  (yB -> gxT region, bf16)
    gemm_kernel<<<dim3(6, 512), 256, 0, stream>>>(
        yB, nullptr, 384, Wa, nullptr, nullptr, keysu, 32768, 384, 384, 1, 0);
    // ctx_vec (flash attention)  (yB, keys -> yA region)
    attn_kernel<<<dim3(32, 32), 256, 0, stream>>>(yB, keysu, ctxvu);
    // combined = tanh([y3, ctx] @ comb_W^T + b)  (-> gxT region, bf16)
    gemm_kernel<<<dim3(6, 512), 256, 0, stream>>>(
        yB, ctxvu, 384, comb_W, comb_b, nullptr, combu, 32768, 384, 768, 2, 0);
    // logits = combined @ fc_W^T + fc_b  (-> d_out, permuted to [b][t][100])
    gemm_kernel<<<dim3(2, 512), 256, 0, stream>>>(
        combu, nullptr, 384, fc_W, fc_b, nullptr, out, 32768, 100, 384, 3, 0);
}